// Round 12
// baseline (190.408 us; speedup 1.0000x reference)
//
#include <hip/hip_runtime.h>

#define B_ 2048
#define T_ 200
#define D_ 64

constexpr int ROWS = 4;             // valid batch rows per block (MFMA M=16, rest padded)
constexpr int NBLK = B_ / ROWS;     // 512 blocks -> 2 per CU, 2 waves/SIMD

typedef _Float16 half_t;
typedef __attribute__((ext_vector_type(8))) _Float16 h8;
typedef __attribute__((ext_vector_type(4))) float f32x4;

// D = A(16x32) * B(32x16) + C, fp16 in / fp32 acc.  [layouts HW-verified r9/r11]
// A: lane l holds A[row=l&15][k=(l>>4)*8+j]
// B: lane l holds B[k=(l>>4)*8+j][col=l&15]
// C/D: lane l holds D[row=(l>>4)*4+reg][col=l&15]
__device__ __forceinline__ f32x4 MF(h8 a, h8 b, f32x4 c) {
  return __builtin_amdgcn_mfma_f32_16x16x32_f16(a, b, c, 0, 0, 0);
}

__device__ __forceinline__ float rcp_(float x) { return __builtin_amdgcn_rcpf(x); }
__device__ __forceinline__ float sigmoidf_(float x) { return rcp_(1.0f + __expf(-x)); }
__device__ __forceinline__ float tanhf_(float x) {
  x = fminf(fmaxf(x, -15.0f), 15.0f);
  const float e = __expf(2.0f * x);
  return (e - 1.0f) * rcp_(e + 1.0f);
}

__device__ __forceinline__ h8 loadB(const float* __restrict__ W, int stride,
                                    int k0, int col) {
  h8 v;
#pragma unroll
  for (int j = 0; j < 8; ++j) v[j] = (half_t)W[(k0 + j) * stride + col];
  return v;
}

// 4 valid rows/block (12 pad rows), 4 waves split the N dimension: wave w owns
// cols 16w..16w+15. Per-wave weights = 12 B-frags = 48 VGPRs (resident).
// Pad rows of sAh/sRh stay zero forever -> finite, row-isolated garbage only.
__global__ __launch_bounds__(256) __attribute__((amdgpu_waves_per_eu(1)))
void augru_mfma4(const float* __restrict__ X, const int* __restrict__ SL,
                 const float* __restrict__ ATT, const float* __restrict__ Wg,
                 const float* __restrict__ bg, const float* __restrict__ Wc,
                 const float* __restrict__ bc, float* __restrict__ OUT) {
  __shared__ __align__(16) half_t sAh[2][512];  // h in A-layout (k 64..127)
  __shared__ __align__(16) half_t sRh[2][512];  // r*h in A-layout

  const int tid = threadIdx.x;
  const int w = tid >> 6;    // wave 0..3
  const int l = tid & 63;
  const int b0 = blockIdx.x * ROWS;
  const int rA = l & 15;     // A row / D col-within-tile
  const int kq = l >> 4;     // k-octet group / D row-quarter
  const int rowD = kq * 4;   // D rows rowD..rowD+3
  const bool act = (rowD < ROWS);  // lanes holding valid D rows (kq==0)
  const int colW = 16 * w + rA;    // this wave's global output column (0..63)
  // A-layout address for element (row=rowD+reg, col=colW):
  const int ksl = colW >> 5;
  const int c32 = colW & 31;
  const int baseA = (rowD + 16 * (c32 >> 3)) * 8 + (c32 & 7);

  // ---- B-fragments in registers (12 x h8 = 48 VGPRs) ----
  const h8 bgr0 = loadB(Wg, 128, 0 + kq * 8, colW);
  const h8 bgr1 = loadB(Wg, 128, 32 + kq * 8, colW);
  const h8 bgr2 = loadB(Wg, 128, 64 + kq * 8, colW);
  const h8 bgr3 = loadB(Wg, 128, 96 + kq * 8, colW);
  const h8 bgu0 = loadB(Wg, 128, 0 + kq * 8, 64 + colW);
  const h8 bgu1 = loadB(Wg, 128, 32 + kq * 8, 64 + colW);
  const h8 bgu2 = loadB(Wg, 128, 64 + kq * 8, 64 + colW);
  const h8 bgu3 = loadB(Wg, 128, 96 + kq * 8, 64 + colW);
  const h8 bcc0 = loadB(Wc, 64, 0 + kq * 8, colW);
  const h8 bcc1 = loadB(Wc, 64, 32 + kq * 8, colW);
  const h8 bcc2 = loadB(Wc, 64, 64 + kq * 8, colW);
  const h8 bcc3 = loadB(Wc, 64, 96 + kq * 8, colW);

  // Zero both h and rh staging tiles (pad rows must stay finite zero).
  {
    h8 z;
#pragma unroll
    for (int j = 0; j < 8; ++j) z[j] = (half_t)0.f;
    ((h8*)&sAh[0][0])[tid & 127] = z;   // 128 h8 = full sAh
    ((h8*)&sRh[0][0])[tid & 127] = z;   // 128 h8 = full sRh
  }

  const float br = bg[colW];
  const float bu = bg[64 + colW];
  const float bcv = bc[colW];

  // Valid-row metadata (clamped for pad lanes; unused there).
  const int rEff = act ? rowD : 0;
  const int L0 = SL[b0 + rEff + 0];
  const int L1 = SL[b0 + ((rEff + 1 < ROWS) ? rEff + 1 : ROWS - 1)];
  const int L2 = SL[b0 + ((rEff + 2 < ROWS) ? rEff + 2 : ROWS - 1)];
  const int L3 = SL[b0 + ((rEff + 3 < ROWS) ? rEff + 3 : ROWS - 1)];
  int Lm = 1;
  for (int r = 0; r < ROWS; ++r) {
    const int v = SL[b0 + r];
    Lm = v > Lm ? v : Lm;
  }

  const int xr = (rA < ROWS) ? rA : ROWS - 1;  // clamp pad A-rows to a real row
  const float* __restrict__ xbase = X + (size_t)(b0 + xr) * (T_ * D_) + kq * 8;
  const float* __restrict__ ap = ATT + (size_t)(b0 + rEff) * T_;
  float* __restrict__ obase = OUT + (size_t)b0 * (T_ * D_);

  // x/att prefetch for t=0
  f32x4 xA0 = *(const f32x4*)(xbase);
  f32x4 xA1 = *(const f32x4*)(xbase + 4);
  f32x4 xB0 = *(const f32x4*)(xbase + 32);
  f32x4 xB1 = *(const f32x4*)(xbase + 36);
  float at0 = ap[0], at1 = ap[T_], at2 = ap[2 * T_], at3 = ap[3 * T_];

  float hd0 = 0.f, hd1 = 0.f, hd2 = 0.f, hd3 = 0.f;

  __syncthreads();  // staging zeros visible

  for (int t = 0; t < Lm; ++t) {
    // h A-fragments (full 16x64 h tile; pad rows are zero)
    const h8 ah0 = ((const h8*)&sAh[0][0])[l];
    const h8 ah1 = ((const h8*)&sAh[1][0])[l];

    // x -> fp16 A-fragments
    h8 ax0, ax1;
#pragma unroll
    for (int j = 0; j < 4; ++j) {
      ax0[j] = (half_t)xA0[j];
      ax0[4 + j] = (half_t)xA1[j];
      ax1[j] = (half_t)xB0[j];
      ax1[4 + j] = (half_t)xB1[j];
    }

    // prefetch t+1 (clamped) — hidden under MFMA chains
    const int tn = (t + 1 < Lm) ? t + 1 : t;
    const f32x4 nA0 = *(const f32x4*)(xbase + tn * 64);
    const f32x4 nA1 = *(const f32x4*)(xbase + tn * 64 + 4);
    const f32x4 nB0 = *(const f32x4*)(xbase + tn * 64 + 32);
    const f32x4 nB1 = *(const f32x4*)(xbase + tn * 64 + 36);
    const float na0 = ap[tn], na1 = ap[T_ + tn], na2 = ap[2 * T_ + tn],
                na3 = ap[3 * T_ + tn];

    // ---- r gate (critical path) ----
    f32x4 gr = {br, br, br, br};
    gr = MF(ax0, bgr0, gr);
    gr = MF(ax1, bgr1, gr);
    gr = MF(ah0, bgr2, gr);
    gr = MF(ah1, bgr3, gr);

    // stage rh = sigmoid(gr) * h_old (valid rows only; pads stay zero)
    if (act) {
      sRh[ksl][baseA + 0 * 8] = (half_t)(sigmoidf_(gr[0]) * hd0);
      sRh[ksl][baseA + 1 * 8] = (half_t)(sigmoidf_(gr[1]) * hd1);
      sRh[ksl][baseA + 2 * 8] = (half_t)(sigmoidf_(gr[2]) * hd2);
      sRh[ksl][baseA + 3 * 8] = (half_t)(sigmoidf_(gr[3]) * hd3);
    }

    // ---- u gate (independent; fills time before the barrier) ----
    f32x4 gu = {bu, bu, bu, bu};
    gu = MF(ax0, bgu0, gu);
    gu = MF(ax1, bgu1, gu);
    gu = MF(ah0, bgu2, gu);
    gu = MF(ah1, bgu3, gu);

    __syncthreads();  // B1: all rh written

    const h8 arh0 = ((const h8*)&sRh[0][0])[l];
    const h8 arh1 = ((const h8*)&sRh[1][0])[l];

    // ---- candidate ----
    f32x4 cc = {bcv, bcv, bcv, bcv};
    cc = MF(ax0, bcc0, cc);
    cc = MF(ax1, bcc1, cc);
    cc = MF(arh0, bcc2, cc);
    cc = MF(arh1, bcc3, cc);

    // ---- blend, mask, store, stage h (valid rows only) ----
    if (act) {
#define FIN(i, HD, AT, LI)                                                  \
  {                                                                         \
    const float uv = sigmoidf_(gu[i]);                                      \
    const float cv = tanhf_(cc[i]);                                         \
    const float hn0 = fmaf(AT * uv, cv - HD, HD);                           \
    const bool ok = t < LI;                                                 \
    const float hn = ok ? hn0 : HD;                                         \
    HD = hn;                                                                \
    obase[(size_t)(rowD + i) * (T_ * D_) + t * 64 + colW] = ok ? hn : 0.0f; \
    sAh[ksl][baseA + i * 8] = (half_t)hn;                                   \
  }
      FIN(0, hd0, at0, L0)
      FIN(1, hd1, at1, L1)
      FIN(2, hd2, at2, L2)
      FIN(3, hd3, at3, L3)
#undef FIN
    }

    __syncthreads();  // B2: all h written before next step's reads

    xA0 = nA0; xA1 = nA1; xB0 = nB0; xB1 = nB1;
    at0 = na0; at1 = na1; at2 = na2; at3 = na3;
  }

  // zero-fill past the block's max length (valid rows only)
  if (act) {
    for (int t = Lm; t < T_; ++t) {
      obase[(size_t)(rowD + 0) * (T_ * D_) + t * 64 + colW] = 0.0f;
      obase[(size_t)(rowD + 1) * (T_ * D_) + t * 64 + colW] = 0.0f;
      obase[(size_t)(rowD + 2) * (T_ * D_) + t * 64 + colW] = 0.0f;
      obase[(size_t)(rowD + 3) * (T_ * D_) + t * 64 + colW] = 0.0f;
    }
  }
}

extern "C" void kernel_launch(void* const* d_in, const int* in_sizes, int n_in,
                              void* d_out, int out_size, void* d_ws, size_t ws_size,
                              hipStream_t stream) {
  (void)in_sizes; (void)n_in; (void)d_ws; (void)ws_size; (void)out_size;
  const float* X  = (const float*)d_in[0];
  const int*   SL = (const int*)d_in[1];
  const float* A  = (const float*)d_in[2];
  const float* Wg = (const float*)d_in[3];
  const float* bg = (const float*)d_in[4];
  const float* Wc = (const float*)d_in[5];
  const float* bc = (const float*)d_in[6];
  float* O = (float*)d_out;

  augru_mfma4<<<NBLK, 256, 0, stream>>>(X, SL, A, Wg, bg, Wc, bc, O);
}

// Round 13
// 178.043 us; speedup vs baseline: 1.0694x; 1.0694x over previous
//
#include <hip/hip_runtime.h>

#define B_ 2048
#define T_ 200
#define D_ 64

constexpr int ROWS = 4;          // valid batch rows per block (MFMA M=16, rest pad)
constexpr int NBLK = B_ / ROWS;  // 512 blocks -> 2 per CU

typedef _Float16 half_t;
typedef __attribute__((ext_vector_type(8))) _Float16 h8;
typedef __attribute__((ext_vector_type(4))) float f32x4;

// D = A(16x32)*B(32x16)+C, fp16 in / fp32 acc. [layouts HW-verified r9/r11/r12]
// A: lane l holds A[row=l&15][k=(l>>4)*8+j]
// B: lane l holds B[k=(l>>4)*8+j][col=l&15]
// C/D: lane l holds D[row=(l>>4)*4+reg][col=l&15]
__device__ __forceinline__ f32x4 MF(h8 a, h8 b, f32x4 c) {
  return __builtin_amdgcn_mfma_f32_16x16x32_f16(a, b, c, 0, 0, 0);
}

__device__ __forceinline__ float rcp_(float x) { return __builtin_amdgcn_rcpf(x); }
__device__ __forceinline__ float sigmoidf_(float x) { return rcp_(1.0f + __expf(-x)); }
__device__ __forceinline__ float tanhf_(float x) {
  x = fminf(fmaxf(x, -15.0f), 15.0f);
  const float e = __expf(2.0f * x);
  return (e - 1.0f) * rcp_(e + 1.0f);
}

__device__ __forceinline__ h8 loadB(const float* __restrict__ W, int stride,
                                    int k0, int col) {
  h8 v;
#pragma unroll
  for (int j = 0; j < 8; ++j) v[j] = (half_t)W[(k0 + j) * stride + col];
  return v;
}

// Software-pipelined MFMA AUGRU:
//  - x-part preactivations (grx/gux/ccx) for step t+1 computed during step t
//    (h-independent) -> off the critical chain.
//  - h-dependent part = 2 parallel MFMAs + f32x4 add -> chain depth 1 MFMA.
//  - 4 valid rows/block, 512 blocks (2/CU) for barrier/LDS latency hiding.
__global__ __launch_bounds__(256, 2)
void augru_pipe4(const float* __restrict__ X, const int* __restrict__ SL,
                 const float* __restrict__ ATT, const float* __restrict__ Wg,
                 const float* __restrict__ bg, const float* __restrict__ Wc,
                 const float* __restrict__ bc, float* __restrict__ OUT) {
  __shared__ __align__(16) half_t sAh[2][512];  // h in A-layout (k 64..127)
  __shared__ __align__(16) half_t sRh[2][512];  // r*h in A-layout

  const int tid = threadIdx.x;
  const int w = tid >> 6;
  const int l = tid & 63;
  const int b0 = blockIdx.x * ROWS;
  const int rA = l & 15;
  const int kq = l >> 4;
  const int rowD = kq * 4;
  const bool act = (rowD < ROWS);  // kq==0 lanes hold the 4 valid D rows
  const int colW = 16 * w + rA;
  const int ksl = colW >> 5;
  const int c32 = colW & 31;
  const int baseA = (rowD + 16 * (c32 >> 3)) * 8 + (c32 & 7);

  // ---- 12 B-fragments in registers (48 VGPRs; proven resident in r11/r12) ----
  const h8 bgr0 = loadB(Wg, 128, 0 + kq * 8, colW);
  const h8 bgr1 = loadB(Wg, 128, 32 + kq * 8, colW);
  const h8 bgr2 = loadB(Wg, 128, 64 + kq * 8, colW);
  const h8 bgr3 = loadB(Wg, 128, 96 + kq * 8, colW);
  const h8 bgu0 = loadB(Wg, 128, 0 + kq * 8, 64 + colW);
  const h8 bgu1 = loadB(Wg, 128, 32 + kq * 8, 64 + colW);
  const h8 bgu2 = loadB(Wg, 128, 64 + kq * 8, 64 + colW);
  const h8 bgu3 = loadB(Wg, 128, 96 + kq * 8, 64 + colW);
  const h8 bcc0 = loadB(Wc, 64, 0 + kq * 8, colW);
  const h8 bcc1 = loadB(Wc, 64, 32 + kq * 8, colW);
  const h8 bcc2 = loadB(Wc, 64, 64 + kq * 8, colW);
  const h8 bcc3 = loadB(Wc, 64, 96 + kq * 8, colW);

  // Zero staging (pad rows must stay finite zero forever).
  {
    h8 z;
#pragma unroll
    for (int j = 0; j < 8; ++j) z[j] = (half_t)0.f;
    ((h8*)&sAh[0][0])[tid & 127] = z;
    ((h8*)&sRh[0][0])[tid & 127] = z;
  }

  const float br = bg[colW];
  const float bu = bg[64 + colW];
  const float bcv = bc[colW];

  const int L0 = SL[b0 + 0];
  const int L1 = SL[b0 + 1];
  const int L2 = SL[b0 + 2];
  const int L3 = SL[b0 + 3];
  int Lm = L0;
  Lm = L1 > Lm ? L1 : Lm;
  Lm = L2 > Lm ? L2 : Lm;
  Lm = L3 > Lm ? L3 : Lm;

  const int xr = (rA < ROWS) ? rA : ROWS - 1;  // clamp pad A-rows
  const float* __restrict__ xbase = X + (size_t)(b0 + xr) * (T_ * D_) + kq * 8;
  const float* __restrict__ ap = ATT + (size_t)b0 * T_;
  float* __restrict__ obase = OUT + (size_t)b0 * (T_ * D_);

  const f32x4 z4 = {0.f, 0.f, 0.f, 0.f};

  // ---- prologue: x(0) -> frags -> x-part preacts for t=0 ----
  f32x4 grx, gux, ccx;
  {
    const f32x4 cA0 = *(const f32x4*)(xbase);
    const f32x4 cA1 = *(const f32x4*)(xbase + 4);
    const f32x4 cB0 = *(const f32x4*)(xbase + 32);
    const f32x4 cB1 = *(const f32x4*)(xbase + 36);
    h8 ax0, ax1;
#pragma unroll
    for (int j = 0; j < 4; ++j) {
      ax0[j] = (half_t)cA0[j];
      ax0[4 + j] = (half_t)cA1[j];
      ax1[j] = (half_t)cB0[j];
      ax1[4 + j] = (half_t)cB1[j];
    }
    f32x4 t0 = {br, br, br, br};
    t0 = MF(ax0, bgr0, t0);
    grx = MF(ax1, bgr1, t0);
    f32x4 t1 = {bu, bu, bu, bu};
    t1 = MF(ax0, bgu0, t1);
    gux = MF(ax1, bgu1, t1);
    f32x4 t2 = {bcv, bcv, bcv, bcv};
    t2 = MF(ax0, bcc0, t2);
    ccx = MF(ax1, bcc1, t2);
  }

  // prefetch x(1), att(0)
  const int i1 = (1 < Lm) ? 1 : 0;
  f32x4 pA0 = *(const f32x4*)(xbase + i1 * 64);
  f32x4 pA1 = *(const f32x4*)(xbase + i1 * 64 + 4);
  f32x4 pB0 = *(const f32x4*)(xbase + i1 * 64 + 32);
  f32x4 pB1 = *(const f32x4*)(xbase + i1 * 64 + 36);
  float at0 = ap[0], at1 = ap[T_], at2 = ap[2 * T_], at3 = ap[3 * T_];

  float hd0 = 0.f, hd1 = 0.f, hd2 = 0.f, hd3 = 0.f;

  __syncthreads();  // staging zeros visible

  for (int t = 0; t < Lm; ++t) {
    // h fragments (pad rows zero)
    const h8 ah0 = ((const h8*)&sAh[0][0])[l];
    const h8 ah1 = ((const h8*)&sAh[1][0])[l];

    // att prefetch t+1
    const int tn = (t + 1 < Lm) ? t + 1 : t;
    const float na0 = ap[tn], na1 = ap[T_ + tn], na2 = ap[2 * T_ + tn],
                na3 = ap[3 * T_ + tn];

    // ---- r gate: h-dep depth = 1 MFMA (two parallel) ----
    const f32x4 grA = MF(ah0, bgr2, grx);
    const f32x4 grB = MF(ah1, bgr3, z4);
    const f32x4 gr = grA + grB;

    if (act) {
      sRh[ksl][baseA + 0 * 8] = (half_t)(sigmoidf_(gr[0]) * hd0);
      sRh[ksl][baseA + 1 * 8] = (half_t)(sigmoidf_(gr[1]) * hd1);
      sRh[ksl][baseA + 2 * 8] = (half_t)(sigmoidf_(gr[2]) * hd2);
      sRh[ksl][baseA + 3 * 8] = (half_t)(sigmoidf_(gr[3]) * hd3);
    }

    // ---- u gate (off-path; fills time before B1) ----
    const f32x4 guA = MF(ah0, bgu2, gux);
    const f32x4 guB = MF(ah1, bgu3, z4);
    const f32x4 gu = guA + guB;

    __syncthreads();  // B1: all rh visible

    const h8 arh0 = ((const h8*)&sRh[0][0])[l];
    const h8 arh1 = ((const h8*)&sRh[1][0])[l];

    // ---- candidate: h-dep depth = 1 MFMA ----
    const f32x4 ccA = MF(arh0, bcc2, ccx);
    const f32x4 ccB = MF(arh1, bcc3, z4);
    const f32x4 cc = ccA + ccB;

    // ---- next step's x-part preacts (off-path; x(t+1) already in regs) ----
    h8 axn0, axn1;
#pragma unroll
    for (int j = 0; j < 4; ++j) {
      axn0[j] = (half_t)pA0[j];
      axn0[4 + j] = (half_t)pA1[j];
      axn1[j] = (half_t)pB0[j];
      axn1[4 + j] = (half_t)pB1[j];
    }
    f32x4 q0 = {br, br, br, br};
    q0 = MF(axn0, bgr0, q0);
    const f32x4 ngrx = MF(axn1, bgr1, q0);
    f32x4 q1 = {bu, bu, bu, bu};
    q1 = MF(axn0, bgu0, q1);
    const f32x4 ngux = MF(axn1, bgu1, q1);
    f32x4 q2 = {bcv, bcv, bcv, bcv};
    q2 = MF(axn0, bcc0, q2);
    const f32x4 nccx = MF(axn1, bcc1, q2);

    // prefetch x(t+2)
    const int tn2 = (t + 2 < Lm) ? t + 2 : Lm - 1;
    const f32x4 qA0 = *(const f32x4*)(xbase + tn2 * 64);
    const f32x4 qA1 = *(const f32x4*)(xbase + tn2 * 64 + 4);
    const f32x4 qB0 = *(const f32x4*)(xbase + tn2 * 64 + 32);
    const f32x4 qB1 = *(const f32x4*)(xbase + tn2 * 64 + 36);

    // ---- blend, mask, store, stage h ----
    if (act) {
#define FIN(i, HD, AT, LI)                                                  \
  {                                                                         \
    const float uv = sigmoidf_(gu[i]);                                      \
    const float cv = tanhf_(cc[i]);                                         \
    const float hn0 = fmaf(AT * uv, cv - HD, HD);                           \
    const bool ok = t < LI;                                                 \
    const float hn = ok ? hn0 : HD;                                         \
    HD = hn;                                                                \
    obase[(size_t)(rowD + i) * (T_ * D_) + t * 64 + colW] = ok ? hn : 0.0f; \
    sAh[ksl][baseA + i * 8] = (half_t)hn;                                   \
  }
      FIN(0, hd0, at0, L0)
      FIN(1, hd1, at1, L1)
      FIN(2, hd2, at2, L2)
      FIN(3, hd3, at3, L3)
#undef FIN
    }

    __syncthreads();  // B2: all h visible for next step

    grx = ngrx; gux = ngux; ccx = nccx;
    pA0 = qA0; pA1 = qA1; pB0 = qB0; pB1 = qB1;
    at0 = na0; at1 = na1; at2 = na2; at3 = na3;
  }

  // zero-fill past the block's max length
  if (act) {
    for (int t = Lm; t < T_; ++t) {
      obase[(size_t)(rowD + 0) * (T_ * D_) + t * 64 + colW] = 0.0f;
      obase[(size_t)(rowD + 1) * (T_ * D_) + t * 64 + colW] = 0.0f;
      obase[(size_t)(rowD + 2) * (T_ * D_) + t * 64 + colW] = 0.0f;
      obase[(size_t)(rowD + 3) * (T_ * D_) + t * 64 + colW] = 0.0f;
    }
  }
}

extern "C" void kernel_launch(void* const* d_in, const int* in_sizes, int n_in,
                              void* d_out, int out_size, void* d_ws, size_t ws_size,
                              hipStream_t stream) {
  (void)in_sizes; (void)n_in; (void)d_ws; (void)ws_size; (void)out_size;
  const float* X  = (const float*)d_in[0];
  const int*   SL = (const int*)d_in[1];
  const float* A  = (const float*)d_in[2];
  const float* Wg = (const float*)d_in[3];
  const float* bg = (const float*)d_in[4];
  const float* Wc = (const float*)d_in[5];
  const float* bc = (const float*)d_in[6];
  float* O = (float*)d_out;

  augru_pipe4<<<NBLK, 256, 0, stream>>>(X, SL, A, Wg, bg, Wc, bc, O);
}